// Round 7
// baseline (978.173 us; speedup 1.0000x reference)
//
#include <hip/hip_runtime.h>

#define BB 32
#define NN 4096
#define CC 768
#define HH 12
#define DD 64
#define QSCALE 0.125f
#define NCHUNK 64            // wpart chunks (64 rows each)

// ws layout (floats)
#define OFF_SB      0           // [B][H]               384
#define OFF_U       384         // [B][H][C]            294912
#define OFF_WPART   295296      // [B][64][H][C]        18874368
#define OFF_W       19169664    // [B][H][C]            294912
#define OFF_XCLSPRE 19464576    // [B][C]               24576
// total 19489152 floats = 78 MB

// ---------------------------------------------------------------------------
// K1: fused q + U.  q[b,h,:] kept in LDS only.
// U[b,h,c] = sum_d Wk[c, h*64+d] * q_d ;  sb[b,h] = q . bk[h-slice]
__global__ __launch_bounds__(256) void k_qU(const float* __restrict__ x,
                                            const float* __restrict__ Wq,
                                            const float* __restrict__ bq,
                                            const float* __restrict__ Wk,
                                            const float* __restrict__ bk,
                                            float* __restrict__ U,
                                            float* __restrict__ sb) {
    int bh = blockIdx.x;
    int b = bh / HH, h = bh % HH;
    int t = threadIdx.x;
    int d = t & 63, cg = t >> 6;
    int col = h * DD + d;
    __shared__ float red[256];
    __shared__ float qs[DD];
    // phase A: q = (x[b,0,:] @ Wq[:,col] + bq) * SCALE
    const float* xr = x + (size_t)b * NN * CC;   // row n=0
    float acc = 0.f;
    #pragma unroll 8
    for (int c = cg * 192; c < cg * 192 + 192; ++c)
        acc += xr[c] * Wq[(size_t)c * CC + col];
    red[t] = acc;
    __syncthreads();
    if (t < 64) {
        float v = red[t] + red[t + 64] + red[t + 128] + red[t + 192];
        qs[t] = (v + bq[col]) * QSCALE;
    }
    __syncthreads();
    // phase B: U row + score bias
    for (int c = t; c < CC; c += 256) {
        const float4* wr = (const float4*)(Wk + (size_t)c * CC + h * DD);
        float a = 0.f;
        #pragma unroll
        for (int d4 = 0; d4 < DD / 4; ++d4) {
            float4 wv = wr[d4];
            a += wv.x * qs[4 * d4] + wv.y * qs[4 * d4 + 1]
               + wv.z * qs[4 * d4 + 2] + wv.w * qs[4 * d4 + 3];
        }
        U[(size_t)bh * CC + c] = a;
    }
    if (t == 0) {
        float a = 0.f;
        for (int d2 = 0; d2 < DD; ++d2) a += qs[d2] * bk[h * DD + d2];
        sb[bh] = a;
    }
}

// ---------------------------------------------------------------------------
// K2: scores[b,h,n] = x[b,n,:] . U[b,h,:] + sb[b,h]
// grid 32b x 32chunks(128 rows); block 512 = 8 waves; wave does 2 rows/iter, 8 iters
__global__ __launch_bounds__(512) void k_scores(const float* __restrict__ x,
                                                const float* __restrict__ U,
                                                const float* __restrict__ sb,
                                                float* __restrict__ scores) {
    int b = blockIdx.x >> 5, chunk = blockIdx.x & 31;
    int n0 = chunk * 128;
    __shared__ float4 U4[HH * 192];   // 36 KB
    __shared__ float sbs[HH];
    int t = threadIdx.x;
    const float4* Ug = (const float4*)(U + (size_t)b * HH * CC);
    for (int i = t; i < HH * 192; i += 512) U4[i] = Ug[i];
    if (t < HH) sbs[t] = sb[b * HH + t];
    __syncthreads();
    int w = t >> 6, l = t & 63;
    #pragma unroll 2
    for (int i = 0; i < 8; ++i) {
        int n = n0 + i * 16 + w * 2;
        const float4* xr0 = (const float4*)(x + ((size_t)b * NN + n) * CC);
        const float4* xr1 = xr0 + 192;
        float4 a0[3], a1[3];
        a0[0] = xr0[l]; a0[1] = xr0[l + 64]; a0[2] = xr0[l + 128];
        a1[0] = xr1[l]; a1[1] = xr1[l + 64]; a1[2] = xr1[l + 128];
        float acc0[HH], acc1[HH];
        #pragma unroll
        for (int h = 0; h < HH; ++h) { acc0[h] = 0.f; acc1[h] = 0.f; }
        #pragma unroll
        for (int k = 0; k < 3; ++k) {
            #pragma unroll
            for (int h = 0; h < HH; ++h) {
                float4 u = U4[h * 192 + k * 64 + l];   // shared across both rows
                acc0[h] += u.x * a0[k].x + u.y * a0[k].y + u.z * a0[k].z + u.w * a0[k].w;
                acc1[h] += u.x * a1[k].x + u.y * a1[k].y + u.z * a1[k].z + u.w * a1[k].w;
            }
        }
        #pragma unroll
        for (int h = 0; h < HH; ++h) {
            float v0 = acc0[h], v1 = acc1[h];
            #pragma unroll
            for (int m = 32; m; m >>= 1) {
                v0 += __shfl_xor(v0, m, 64);
                v1 += __shfl_xor(v1, m, 64);
            }
            acc0[h] = v0; acc1[h] = v1;
        }
        float out0 = 0.f, out1 = 0.f;
        #pragma unroll
        for (int h = 0; h < HH; ++h)
            if (l == h) { out0 = acc0[h]; out1 = acc1[h]; }   // static idx (rule #20)
        if (l < HH) {
            scores[((size_t)b * HH + l) * NN + n]     = out0 + sbs[l];
            scores[((size_t)b * HH + l) * NN + n + 1] = out1 + sbs[l];
        }
    }
}

// ---------------------------------------------------------------------------
// K3: in-place softmax over each row of attn[b*H+h][0..N)
__global__ __launch_bounds__(256) void k_softmax(float* __restrict__ attn) {
    int bh = blockIdx.x;
    float4* row = (float4*)(attn + (size_t)bh * NN);
    int t = threadIdx.x;
    float4 v[4];
    #pragma unroll
    for (int i = 0; i < 4; ++i) v[i] = row[t + 256 * i];
    float m = -1e30f;
    #pragma unroll
    for (int i = 0; i < 4; ++i)
        m = fmaxf(m, fmaxf(fmaxf(v[i].x, v[i].y), fmaxf(v[i].z, v[i].w)));
    #pragma unroll
    for (int mm = 32; mm; mm >>= 1) m = fmaxf(m, __shfl_xor(m, mm, 64));
    __shared__ float redm[4], reds[4];
    int w = t >> 6, l = t & 63;
    if (l == 0) redm[w] = m;
    __syncthreads();
    m = fmaxf(fmaxf(redm[0], redm[1]), fmaxf(redm[2], redm[3]));
    float s = 0.f;
    #pragma unroll
    for (int i = 0; i < 4; ++i) {
        v[i].x = __expf(v[i].x - m); v[i].y = __expf(v[i].y - m);
        v[i].z = __expf(v[i].z - m); v[i].w = __expf(v[i].w - m);
        s += v[i].x + v[i].y + v[i].z + v[i].w;
    }
    #pragma unroll
    for (int mm = 32; mm; mm >>= 1) s += __shfl_xor(s, mm, 64);
    if (l == 0) reds[w] = s;
    __syncthreads();
    float inv = 1.f / (reds[0] + reds[1] + reds[2] + reds[3]);
    #pragma unroll
    for (int i = 0; i < 4; ++i) {
        v[i].x *= inv; v[i].y *= inv; v[i].z *= inv; v[i].w *= inv;
        row[t + 256 * i] = v[i];
    }
}

// ---------------------------------------------------------------------------
// K4: wpart[b,chunk,h,c] = sum_{n in chunk(64)} attn[b,h,n] * x[b,n,c]
// grid 32b x 64chunks = 2048 blocks (8/CU); block 192 thr; thread owns float4 col t.
#define FMA4(A, s, X) { (A).x += (s)*(X).x; (A).y += (s)*(X).y; (A).z += (s)*(X).z; (A).w += (s)*(X).w; }
__global__ __launch_bounds__(192) void k_wpart(const float* __restrict__ x,
                                               const float* __restrict__ attn,
                                               float* __restrict__ wpart) {
    int b = blockIdx.x >> 6, chunk = blockIdx.x & 63;
    int n0 = chunk * 64;
    __shared__ float al[64][HH];   // [n][h], 3 KB; 48B rows -> float4-aligned
    int t = threadIdx.x;           // 0..191
    const float* ag = attn + (size_t)b * HH * NN + n0;
    for (int i = t; i < HH * 64; i += 192) {
        int h = i >> 6, n = i & 63;
        al[n][h] = ag[(size_t)h * NN + n];
    }
    __syncthreads();
    float4 acc[HH];
    #pragma unroll
    for (int h = 0; h < HH; ++h) acc[h] = make_float4(0.f, 0.f, 0.f, 0.f);
    const float4* xb = (const float4*)(x + ((size_t)b * NN + n0) * CC);
    #pragma unroll 2
    for (int n = 0; n < 64; ++n) {
        float4 xv = xb[(size_t)n * 192 + t];
        float4 a0 = *(const float4*)&al[n][0];   // heads 0..3  (uniform addr: broadcast)
        float4 a1 = *(const float4*)&al[n][4];   // heads 4..7
        float4 a2 = *(const float4*)&al[n][8];   // heads 8..11
        FMA4(acc[0],  a0.x, xv); FMA4(acc[1],  a0.y, xv);
        FMA4(acc[2],  a0.z, xv); FMA4(acc[3],  a0.w, xv);
        FMA4(acc[4],  a1.x, xv); FMA4(acc[5],  a1.y, xv);
        FMA4(acc[6],  a1.z, xv); FMA4(acc[7],  a1.w, xv);
        FMA4(acc[8],  a2.x, xv); FMA4(acc[9],  a2.y, xv);
        FMA4(acc[10], a2.z, xv); FMA4(acc[11], a2.w, xv);
    }
    float4* wp = (float4*)(wpart + (((size_t)b * NCHUNK + chunk) * HH) * CC);
    #pragma unroll
    for (int h = 0; h < HH; ++h)
        wp[h * 192 + t] = acc[h];
}

// ---------------------------------------------------------------------------
// K5: w[b,h,c] = sum_ch wpart[b,ch,h,c].  One float per thread, grid 1152.
__global__ __launch_bounds__(256) void k_wsum(const float* __restrict__ wpart,
                                              float* __restrict__ w) {
    int i = blockIdx.x * 256 + threadIdx.x;        // < B*H*C = 294912
    int b = i / (HH * CC), r = i - b * (HH * CC);
    const float* p = wpart + (size_t)b * NCHUNK * HH * CC + r;
    float s = 0.f;
    #pragma unroll 8
    for (int ch = 0; ch < NCHUNK; ++ch)
        s += p[(size_t)ch * HH * CC];
    w[i] = s;
}

// ---------------------------------------------------------------------------
// K6: xclspre[b, h*64+d] = w[b,h,:] . Wv[:, h*64+d] + bv
__global__ __launch_bounds__(256) void k_xcls2(const float* __restrict__ w,
                                               const float* __restrict__ Wv,
                                               const float* __restrict__ bv,
                                               float* __restrict__ xclspre) {
    int bh = blockIdx.x, b = bh / HH, h = bh % HH;
    __shared__ float wl[CC];
    __shared__ float red[256];
    int t = threadIdx.x;
    for (int c = t; c < CC; c += 256) wl[c] = w[(size_t)bh * CC + c];
    __syncthreads();
    int d = t & 63, cg = t >> 6;
    int col = h * DD + d;
    float acc = 0.f;
    #pragma unroll 8
    for (int c = cg * 192; c < cg * 192 + 192; ++c)
        acc += wl[c] * Wv[(size_t)c * CC + col];
    red[t] = acc;
    __syncthreads();
    if (t < 64)
        xclspre[b * CC + col] = red[t] + red[t + 64] + red[t + 128] + red[t + 192] + bv[col];
}

// ---------------------------------------------------------------------------
// K7: out[b,j] = xclspre[b,:] @ Wp[:,j] + bp[j]
__global__ __launch_bounds__(256) void k_proj(const float* __restrict__ xclspre,
                                              const float* __restrict__ Wp,
                                              const float* __restrict__ bp,
                                              float* __restrict__ out) {
    int blk = blockIdx.x, b = blk / 12, jg = blk % 12;
    __shared__ float xs[CC];
    __shared__ float red[256];
    int t = threadIdx.x;
    for (int c = t; c < CC; c += 256) xs[c] = xclspre[b * CC + c];
    __syncthreads();
    int d = t & 63, cg = t >> 6;
    int j = jg * DD + d;
    float acc = 0.f;
    #pragma unroll 8
    for (int c = cg * 192; c < cg * 192 + 192; ++c)
        acc += xs[c] * Wp[(size_t)c * CC + j];
    red[t] = acc;
    __syncthreads();
    if (t < 64)
        out[b * CC + j] = red[t] + red[t + 64] + red[t + 128] + red[t + 192] + bp[j];
}

// ---------------------------------------------------------------------------
extern "C" void kernel_launch(void* const* d_in, const int* in_sizes, int n_in,
                              void* d_out, int out_size, void* d_ws, size_t ws_size,
                              hipStream_t stream) {
    const float* x  = (const float*)d_in[0];
    const float* Wq = (const float*)d_in[1];
    const float* bq = (const float*)d_in[2];
    const float* Wk = (const float*)d_in[3];
    const float* bk = (const float*)d_in[4];
    const float* Wv = (const float*)d_in[5];
    const float* bv = (const float*)d_in[6];
    const float* Wp = (const float*)d_in[7];
    const float* bp = (const float*)d_in[8];
    float* out = (float*)d_out;
    float* ws  = (float*)d_ws;

    float* sb      = ws + OFF_SB;
    float* U       = ws + OFF_U;
    float* wpart   = ws + OFF_WPART;
    float* w       = ws + OFF_W;
    float* xclspre = ws + OFF_XCLSPRE;

    float* xcls = out;              // [B][C]
    float* attn = out + BB * CC;    // [B][H][N] — scores written here, softmaxed in place

    hipLaunchKernelGGL(k_qU,      dim3(BB * HH), dim3(256), 0, stream, x, Wq, bq, Wk, bk, U, sb);
    hipLaunchKernelGGL(k_scores,  dim3(BB * 32), dim3(512), 0, stream, x, U, sb, attn);
    hipLaunchKernelGGL(k_softmax, dim3(BB * HH), dim3(256), 0, stream, attn);
    hipLaunchKernelGGL(k_wpart,   dim3(BB * NCHUNK), dim3(192), 0, stream, x, attn, wpart);
    hipLaunchKernelGGL(k_wsum,    dim3(BB * HH * CC / 256), dim3(256), 0, stream, wpart, w);
    hipLaunchKernelGGL(k_xcls2,   dim3(BB * HH), dim3(256), 0, stream, w, Wv, bv, xclspre);
    hipLaunchKernelGGL(k_proj,    dim3(BB * 12), dim3(256), 0, stream, xclspre, Wp, bp, xcls);
}

// Round 8
// 864.782 us; speedup vs baseline: 1.1311x; 1.1311x over previous
//
#include <hip/hip_runtime.h>

#define BB 32
#define NN 4096
#define CC 768
#define HH 12
#define DD 64
#define QSCALE 0.125f
#define NCHUNK 64            // wpart chunks (64 rows each)

// ws layout (floats)
#define OFF_SB      0           // [B][H]               384
#define OFF_U       384         // [B][H][C]            294912
#define OFF_WPART   295296      // [B][64][H][C]        18874368
#define OFF_W       19169664    // [B][H][C]            294912
#define OFF_XCLSPRE 19464576    // [B][C]               24576
// total 19489152 floats = 78 MB

__device__ __forceinline__ unsigned int pack2bf(float a, float b) {
    unsigned int ua = __float_as_uint(a), ub = __float_as_uint(b);
    ua = (ua + 0x7fffu + ((ua >> 16) & 1u)) >> 16;      // RNE to bf16
    ub = (ub + 0x7fffu + ((ub >> 16) & 1u)) >> 16;
    return ua | (ub << 16);
}
#define BLO(u) __uint_as_float((u) << 16)
#define BHI(u) __uint_as_float((u) & 0xffff0000u)

// ---------------------------------------------------------------------------
// K1: fused q + U.  q[b,h,:] kept in LDS only.
// U[b,h,c] = sum_d Wk[c, h*64+d] * q_d ;  sb[b,h] = q . bk[h-slice]
__global__ __launch_bounds__(256) void k_qU(const float* __restrict__ x,
                                            const float* __restrict__ Wq,
                                            const float* __restrict__ bq,
                                            const float* __restrict__ Wk,
                                            const float* __restrict__ bk,
                                            float* __restrict__ U,
                                            float* __restrict__ sb) {
    int bh = blockIdx.x;
    int b = bh / HH, h = bh % HH;
    int t = threadIdx.x;
    int d = t & 63, cg = t >> 6;
    int col = h * DD + d;
    __shared__ float red[256];
    __shared__ float qs[DD];
    const float* xr = x + (size_t)b * NN * CC;   // row n=0
    float acc = 0.f;
    #pragma unroll 8
    for (int c = cg * 192; c < cg * 192 + 192; ++c)
        acc += xr[c] * Wq[(size_t)c * CC + col];
    red[t] = acc;
    __syncthreads();
    if (t < 64) {
        float v = red[t] + red[t + 64] + red[t + 128] + red[t + 192];
        qs[t] = (v + bq[col]) * QSCALE;
    }
    __syncthreads();
    for (int c = t; c < CC; c += 256) {
        const float4* wr = (const float4*)(Wk + (size_t)c * CC + h * DD);
        float a = 0.f;
        #pragma unroll
        for (int d4 = 0; d4 < DD / 4; ++d4) {
            float4 wv = wr[d4];
            a += wv.x * qs[4 * d4] + wv.y * qs[4 * d4 + 1]
               + wv.z * qs[4 * d4 + 2] + wv.w * qs[4 * d4 + 3];
        }
        U[(size_t)bh * CC + c] = a;
    }
    if (t == 0) {
        float a = 0.f;
        for (int d2 = 0; d2 < DD; ++d2) a += qs[d2] * bk[h * DD + d2];
        sb[bh] = a;
    }
}

// ---------------------------------------------------------------------------
// K2 v4: scores[b,h,n] = x[b,n,:] . U[b,h,:] + sb[b,h]
// grid 32b x 64chunks(64 rows) = 2048 blocks; block 256 = 4 waves.
// Lane = (p,q): head p (0..15, 12 real), col-quarter q (0..3). One row/wave-iter.
// U staged in LDS as packed bf16 (24 KB). Reduce = 2 shfl. Store via LDS tile,
// flushed as contiguous 256B runs per head (full-line writes).
__global__ __launch_bounds__(256, 5) void k_scores(const float* __restrict__ x,
                                                   const float* __restrict__ U,
                                                   const float* __restrict__ sb,
                                                   float* __restrict__ scores) {
    __shared__ uint4 ut8[96 * 16];   // [colgroup G][head p], 8 bf16 each; 24576 B
    __shared__ float sc[12 * 65];    // [h][row] staging, padded; 3120 B
    __shared__ float sbs[12];
    int b = blockIdx.x >> 6, chunk = blockIdx.x & 63;
    int n0 = chunk * 64;
    int t = threadIdx.x;

    // stage U -> packed bf16 LDS
    const float4* Ug4 = (const float4*)(U + (size_t)b * HH * CC);
    for (int i = t; i < 96 * 12; i += 256) {
        int h = i / 96, G = i - h * 96;
        float4 a = Ug4[h * 192 + 2 * G];
        float4 c = Ug4[h * 192 + 2 * G + 1];
        ut8[(G << 4) | h] = make_uint4(pack2bf(a.x, a.y), pack2bf(a.z, a.w),
                                       pack2bf(c.x, c.y), pack2bf(c.z, c.w));
    }
    for (int i = t; i < 96 * 4; i += 256) {          // zero pad heads 12..15
        int h = 12 + i / 96, G = i - (h - 12) * 96;
        ut8[(G << 4) | h] = make_uint4(0u, 0u, 0u, 0u);
    }
    if (t < 12) sbs[t] = sb[b * HH + t];
    __syncthreads();

    int w = t >> 6, l = t & 63;
    int p = l & 15, q = l >> 4;
    for (int i = 0; i < 16; ++i) {
        int rloc = w * 16 + i;                       // 0..63
        int n = n0 + rloc;
        const float4* xrow = (const float4*)(x + ((size_t)b * NN + n) * CC);
        float acc = 0.f;
        #pragma unroll 4
        for (int g = 0; g < 24; ++g) {
            int G = q * 24 + g;
            float4 xa = xrow[2 * G];
            float4 xb = xrow[2 * G + 1];
            uint4 u = ut8[(G << 4) | p];
            acc += xa.x * BLO(u.x) + xa.y * BHI(u.x)
                 + xa.z * BLO(u.y) + xa.w * BHI(u.y)
                 + xb.x * BLO(u.z) + xb.y * BHI(u.z)
                 + xb.z * BLO(u.w) + xb.w * BHI(u.w);
        }
        acc += __shfl_xor(acc, 16, 64);
        acc += __shfl_xor(acc, 32, 64);
        if (l < 12) sc[l * 65 + rloc] = acc;         // q==0 lanes, head l
    }
    __syncthreads();
    // flush: 12 heads x 64 cols = 768 floats; 3 per thread; 256B contiguous runs
    int h = t >> 6, n_ = t & 63;
    #pragma unroll
    for (int j = 0; j < 3; ++j) {
        int hh = h + 4 * j;
        scores[((size_t)b * HH + hh) * NN + n0 + n_] = sc[hh * 65 + n_] + sbs[hh];
    }
}

// ---------------------------------------------------------------------------
// K3: in-place softmax over each row of attn[b*H+h][0..N)
__global__ __launch_bounds__(256) void k_softmax(float* __restrict__ attn) {
    int bh = blockIdx.x;
    float4* row = (float4*)(attn + (size_t)bh * NN);
    int t = threadIdx.x;
    float4 v[4];
    #pragma unroll
    for (int i = 0; i < 4; ++i) v[i] = row[t + 256 * i];
    float m = -1e30f;
    #pragma unroll
    for (int i = 0; i < 4; ++i)
        m = fmaxf(m, fmaxf(fmaxf(v[i].x, v[i].y), fmaxf(v[i].z, v[i].w)));
    #pragma unroll
    for (int mm = 32; mm; mm >>= 1) m = fmaxf(m, __shfl_xor(m, mm, 64));
    __shared__ float redm[4], reds[4];
    int w = t >> 6, l = t & 63;
    if (l == 0) redm[w] = m;
    __syncthreads();
    m = fmaxf(fmaxf(redm[0], redm[1]), fmaxf(redm[2], redm[3]));
    float s = 0.f;
    #pragma unroll
    for (int i = 0; i < 4; ++i) {
        v[i].x = __expf(v[i].x - m); v[i].y = __expf(v[i].y - m);
        v[i].z = __expf(v[i].z - m); v[i].w = __expf(v[i].w - m);
        s += v[i].x + v[i].y + v[i].z + v[i].w;
    }
    #pragma unroll
    for (int mm = 32; mm; mm >>= 1) s += __shfl_xor(s, mm, 64);
    if (l == 0) reds[w] = s;
    __syncthreads();
    float inv = 1.f / (reds[0] + reds[1] + reds[2] + reds[3]);
    #pragma unroll
    for (int i = 0; i < 4; ++i) {
        v[i].x *= inv; v[i].y *= inv; v[i].z *= inv; v[i].w *= inv;
        row[t + 256 * i] = v[i];
    }
}

// ---------------------------------------------------------------------------
// K4: wpart[b,chunk,h,c] = sum_{n in chunk(64)} attn[b,h,n] * x[b,n,c]
// grid 32b x 64chunks = 2048 blocks; block 192 thr; thread owns float4 col t.
#define FMA4(A, s, X) { (A).x += (s)*(X).x; (A).y += (s)*(X).y; (A).z += (s)*(X).z; (A).w += (s)*(X).w; }
__global__ __launch_bounds__(192) void k_wpart(const float* __restrict__ x,
                                               const float* __restrict__ attn,
                                               float* __restrict__ wpart) {
    int b = blockIdx.x >> 6, chunk = blockIdx.x & 63;
    int n0 = chunk * 64;
    __shared__ float al[64][HH];   // [n][h], 3 KB; 48B rows -> float4-aligned
    int t = threadIdx.x;           // 0..191
    const float* ag = attn + (size_t)b * HH * NN + n0;
    for (int i = t; i < HH * 64; i += 192) {
        int h = i >> 6, n = i & 63;
        al[n][h] = ag[(size_t)h * NN + n];
    }
    __syncthreads();
    float4 acc[HH];
    #pragma unroll
    for (int h = 0; h < HH; ++h) acc[h] = make_float4(0.f, 0.f, 0.f, 0.f);
    const float4* xb = (const float4*)(x + ((size_t)b * NN + n0) * CC);
    #pragma unroll 2
    for (int n = 0; n < 64; ++n) {
        float4 xv = xb[(size_t)n * 192 + t];
        float4 a0 = *(const float4*)&al[n][0];
        float4 a1 = *(const float4*)&al[n][4];
        float4 a2 = *(const float4*)&al[n][8];
        FMA4(acc[0],  a0.x, xv); FMA4(acc[1],  a0.y, xv);
        FMA4(acc[2],  a0.z, xv); FMA4(acc[3],  a0.w, xv);
        FMA4(acc[4],  a1.x, xv); FMA4(acc[5],  a1.y, xv);
        FMA4(acc[6],  a1.z, xv); FMA4(acc[7],  a1.w, xv);
        FMA4(acc[8],  a2.x, xv); FMA4(acc[9],  a2.y, xv);
        FMA4(acc[10], a2.z, xv); FMA4(acc[11], a2.w, xv);
    }
    float4* wp = (float4*)(wpart + (((size_t)b * NCHUNK + chunk) * HH) * CC);
    #pragma unroll
    for (int h = 0; h < HH; ++h)
        wp[h * 192 + t] = acc[h];
}

// ---------------------------------------------------------------------------
// K5: w[b,h,c] = sum_ch wpart[b,ch,h,c].  One float per thread, grid 1152.
__global__ __launch_bounds__(256) void k_wsum(const float* __restrict__ wpart,
                                              float* __restrict__ w) {
    int i = blockIdx.x * 256 + threadIdx.x;        // < B*H*C = 294912
    int b = i / (HH * CC), r = i - b * (HH * CC);
    const float* p = wpart + (size_t)b * NCHUNK * HH * CC + r;
    float s = 0.f;
    #pragma unroll 8
    for (int ch = 0; ch < NCHUNK; ++ch)
        s += p[(size_t)ch * HH * CC];
    w[i] = s;
}

// ---------------------------------------------------------------------------
// K6: xclspre[b, h*64+d] = w[b,h,:] . Wv[:, h*64+d] + bv
__global__ __launch_bounds__(256) void k_xcls2(const float* __restrict__ w,
                                               const float* __restrict__ Wv,
                                               const float* __restrict__ bv,
                                               float* __restrict__ xclspre) {
    int bh = blockIdx.x, b = bh / HH, h = bh % HH;
    __shared__ float wl[CC];
    __shared__ float red[256];
    int t = threadIdx.x;
    for (int c = t; c < CC; c += 256) wl[c] = w[(size_t)bh * CC + c];
    __syncthreads();
    int d = t & 63, cg = t >> 6;
    int col = h * DD + d;
    float acc = 0.f;
    #pragma unroll 8
    for (int c = cg * 192; c < cg * 192 + 192; ++c)
        acc += wl[c] * Wv[(size_t)c * CC + col];
    red[t] = acc;
    __syncthreads();
    if (t < 64)
        xclspre[b * CC + col] = red[t] + red[t + 64] + red[t + 128] + red[t + 192] + bv[col];
}

// ---------------------------------------------------------------------------
// K7: out[b,j] = xclspre[b,:] @ Wp[:,j] + bp[j]
__global__ __launch_bounds__(256) void k_proj(const float* __restrict__ xclspre,
                                              const float* __restrict__ Wp,
                                              const float* __restrict__ bp,
                                              float* __restrict__ out) {
    int blk = blockIdx.x, b = blk / 12, jg = blk % 12;
    __shared__ float xs[CC];
    __shared__ float red[256];
    int t = threadIdx.x;
    for (int c = t; c < CC; c += 256) xs[c] = xclspre[b * CC + c];
    __syncthreads();
    int d = t & 63, cg = t >> 6;
    int j = jg * DD + d;
    float acc = 0.f;
    #pragma unroll 8
    for (int c = cg * 192; c < cg * 192 + 192; ++c)
        acc += xs[c] * Wp[(size_t)c * CC + j];
    red[t] = acc;
    __syncthreads();
    if (t < 64)
        out[b * CC + j] = red[t] + red[t + 64] + red[t + 128] + red[t + 192] + bp[j];
}

// ---------------------------------------------------------------------------
extern "C" void kernel_launch(void* const* d_in, const int* in_sizes, int n_in,
                              void* d_out, int out_size, void* d_ws, size_t ws_size,
                              hipStream_t stream) {
    const float* x  = (const float*)d_in[0];
    const float* Wq = (const float*)d_in[1];
    const float* bq = (const float*)d_in[2];
    const float* Wk = (const float*)d_in[3];
    const float* bk = (const float*)d_in[4];
    const float* Wv = (const float*)d_in[5];
    const float* bv = (const float*)d_in[6];
    const float* Wp = (const float*)d_in[7];
    const float* bp = (const float*)d_in[8];
    float* out = (float*)d_out;
    float* ws  = (float*)d_ws;

    float* sb      = ws + OFF_SB;
    float* U       = ws + OFF_U;
    float* wpart   = ws + OFF_WPART;
    float* w       = ws + OFF_W;
    float* xclspre = ws + OFF_XCLSPRE;

    float* xcls = out;              // [B][C]
    float* attn = out + BB * CC;    // [B][H][N] — scores written here, softmaxed in place

    hipLaunchKernelGGL(k_qU,      dim3(BB * HH), dim3(256), 0, stream, x, Wq, bq, Wk, bk, U, sb);
    hipLaunchKernelGGL(k_scores,  dim3(BB * 64), dim3(256), 0, stream, x, U, sb, attn);
    hipLaunchKernelGGL(k_softmax, dim3(BB * HH), dim3(256), 0, stream, attn);
    hipLaunchKernelGGL(k_wpart,   dim3(BB * NCHUNK), dim3(192), 0, stream, x, attn, wpart);
    hipLaunchKernelGGL(k_wsum,    dim3(BB * HH * CC / 256), dim3(256), 0, stream, wpart, w);
    hipLaunchKernelGGL(k_xcls2,   dim3(BB * HH), dim3(256), 0, stream, w, Wv, bv, xclspre);
    hipLaunchKernelGGL(k_proj,    dim3(BB * 12), dim3(256), 0, stream, xclspre, Wp, bp, xcls);
}